// Round 6
// baseline (561.599 us; speedup 1.0000x reference)
//
#include <hip/hip_runtime.h>

typedef unsigned short u16;
typedef unsigned int u32;
typedef unsigned char u8;
typedef __attribute__((ext_vector_type(4))) float f32x4;

// Clamp two floats to +-448 and pack as OCP e4m3fn into half of a u32 via the
// HW converter (RNE). HI selector must be a compile-time constant.
template <bool HI>
__device__ __forceinline__ u32 q2fp8(float a, float b, u32 old, float s) {
  a = fminf(448.0f, fmaxf(-448.0f, a * s));
  b = fminf(448.0f, fmaxf(-448.0f, b * s));
  return (u32)__builtin_amdgcn_cvt_pk_fp8_f32(a, b, (int)old, HI);
}

__device__ __forceinline__ float block_max(float m) {
#pragma unroll
  for (int off = 32; off > 0; off >>= 1)
    m = fmaxf(m, __shfl_down(m, off, 64));
  __shared__ float sm[4];
  int wv = threadIdx.x >> 6;
  if ((threadIdx.x & 63) == 0) sm[wv] = m;
  __syncthreads();
  float r = fmaxf(fmaxf(sm[0], sm[1]), fmaxf(sm[2], sm[3]));
  __syncthreads();
  return r;
}

#define XBLOCKS 2048
#define WBLOCKS 64

// blocks [0,2048): amax partials over x; [2048,2112): over w. No atomics, no init.
__global__ void amax2_kernel(const float4* __restrict__ x, int nx4,
                             const float4* __restrict__ w, int nw4,
                             float* __restrict__ px, float* __restrict__ pw) {
  int bid = blockIdx.x;
  const float4* p;
  int n4, b, nb;
  float* dst;
  if (bid < XBLOCKS) { p = x; n4 = nx4; dst = px; b = bid; nb = XBLOCKS; }
  else { p = w; n4 = nw4; dst = pw; b = bid - XBLOCKS; nb = WBLOCKS; }
  float m = 0.0f;
  int stride = nb * 256;
  for (int i = b * 256 + threadIdx.x; i < n4; i += stride) {
    float4 v = p[i];
    m = fmaxf(m, fmaxf(fmaxf(fabsf(v.x), fabsf(v.y)), fmaxf(fabsf(v.z), fabsf(v.w))));
  }
  m = block_max(m);
  if (threadIdx.x == 0) dst[b] = m;
}

// Full-wave max of 64 partials (bit-exact fmax reduction, order-independent).
__device__ __forceinline__ float wave_max64(float m) {
#pragma unroll
  for (int off = 32; off > 0; off >>= 1) m = fmaxf(m, __shfl_xor(m, off, 64));
  return m;
}

// Quantize w to fp8 e4m3 in a TILED layout: wq[kc][n][8] with kc = k>>3, i.e.
// wq[kc*4096 + n*8 + (k&7)] = q(w[n][k]). Computes sw from the pw partials
// itself (wave-local butterfly; fmax is exact so identical across kernels).
__global__ void quant_w_kernel(const float* __restrict__ w, u8* __restrict__ wq,
                               const float* __restrict__ pw) {
  float mw = wave_max64(pw[threadIdx.x & 63]);
  const float sw = mw > 0.0f ? 448.0f / mw * 0.9f : 1.0f;
  const int id = blockIdx.x * blockDim.x + threadIdx.x;  // 32768 = 64 kc * 512 n
  const int kc = id >> 9;
  const int n = id & 511;
  const float4* src = (const float4*)(w + (size_t)n * 512 + kc * 8);
  const float4 a = src[0];
  const float4 b = src[1];
  uint2 r;
  r.x = q2fp8<false>(a.x, a.y, 0u, sw);
  r.x = q2fp8<true>(a.z, a.w, r.x, sw);
  r.y = q2fp8<false>(b.x, b.y, 0u, sw);
  r.y = q2fp8<true>(b.z, b.w, r.y, sw);
  *(uint2*)&wq[(size_t)kc * 4096 + n * 8] = r;
}

// C = (q(x) @ q(w)^T + bias) * inv, fp8 MFMA.  BM=128, BN=256, BK=64, 512 thr
// (8 waves 2x4; wave computes 64x64 = 4x4 16x16 tiles, acc = 64 VGPR).
// All vmem waits are >=1 iteration old:
//   - x register-prefetched 2 iterations ahead (xr[2][4], compile-time indexed);
//   - B staged 2 tiles ahead into a 3-deep LDS ring via global_load_lds;
//   - raw s_barrier + counted s_waitcnt vmcnt(6): leaves x(kt+2)+B(kt+2) in
//     flight across the barrier; proves B(kt+1) (issued last iter) landed.
// A tile [c:4][128][16] fp8: one ds_write_b128 per thread per tile; fragment
// ds_read_b64 <=2-way bank aliasing (free). Scales reduced in-kernel from
// px/pw partials (reads issued before the reduce's wait, prologue loads after,
// so the prologue x/B loads stay in flight through the reduce).
// LDS 64 KB -> 2 blocks/CU; 4 waves/EU. T5 setprio around each MFMA cluster.
// Grid swizzle: the 2 blocks sharing an x row-tile have linear ids differing by
// 8 -> same XCD under round-robin dispatch -> 2nd x read hits that XCD's L2.
__global__ void __launch_bounds__(512, 4) gemm_kernel(const float* __restrict__ x,
                                                      const u8* __restrict__ wq,
                                                      const float* __restrict__ bias,
                                                      float* __restrict__ out,
                                                      const float* __restrict__ px,
                                                      const float* __restrict__ pw) {
  __shared__ __align__(16) u8 As[2 * 8192];    // [bu:2][c:4][128][16] fp8, 16 KB
  __shared__ __align__(16) u8 Bs[3 * 16384];   // [bu:3][c:8][256][8]  fp8, 48 KB
  __shared__ float sm8[8];
  const int tid = threadIdx.x;
  const int lane = tid & 63;
  const int wv = tid >> 6;          // 0..7
  const int quad = lane >> 4;
  const int lr = lane & 15;

  const int lin = blockIdx.x;
  const int xcd = lin & 7;
  const int jn = (lin >> 3) & 1;
  const int grp = lin >> 4;
  const int m0 = (grp * 8 + xcd) * 128;
  const int n0 = jn * 256;

  const int wm = (wv >> 2) * 64;    // wave row: 0 or 64
  const int wn = (wv & 3) * 64;     // wave col: 0,64,128,192
  const int xrow = tid >> 2;        // 0..127
  const int xc = tid & 3;           // 16-wide k-chunk this thread fills

  f32x4 acc[4][4] = {};
  float4 xr[2][4];                  // [slot][4xfloat4] -- compile-time indexed

  // ---- scale partial reads FIRST (their wait leaves later loads in flight) ----
  float pxv[4];
#pragma unroll
  for (int i = 0; i < 4; ++i) pxv[i] = px[tid + i * 512];
  float pwv = pw[lane];

  // ---- stage w tile (16 KB) for k-step kt into ring buffer bu; wave wv owns chunk wv ----
  auto stageB = [&](int bu, int kt) {
#pragma unroll
    for (int i = 0; i < 2; ++i) {
      const u8* gp = wq + (size_t)(kt * 8 + wv) * 4096 + (size_t)n0 * 8 + i * 1024 + lane * 16;
      u8* lp = &Bs[bu * 16384 + wv * 2048 + i * 1024 + lane * 16];
      __builtin_amdgcn_global_load_lds((const __attribute__((address_space(1))) u32*)gp,
                                       (__attribute__((address_space(3))) u32*)lp, 16, 0, 0);
    }
  };
  // ---- issue x fp32 loads (64 B/thread, 16 consecutive floats) into slot ----
  auto loadX = [&](int slot, int kt) {
    const float* p = x + (size_t)(m0 + xrow) * 512 + kt * 64 + xc * 16;
#pragma unroll
    for (int s = 0; s < 4; ++s) xr[slot][s] = *(const float4*)(p + s * 4);
  };

  // ---- prologue loads: x(0)->slot0, x(1)->slot1, B(0), B(1) ----
  loadX(0, 0);
  loadX(1, 1);
  stageB(0, 0);
  stageB(1, 1);

  // ---- reduce scales (waits only the px/pw reads; x/B stay outstanding) ----
  float m = fmaxf(fmaxf(pxv[0], pxv[1]), fmaxf(pxv[2], pxv[3]));
  m = wave_max64(m);
  if (lane == 0) sm8[wv] = m;
  __syncthreads();
  float mx = sm8[0];
#pragma unroll
  for (int i = 1; i < 8; ++i) mx = fmaxf(mx, sm8[i]);
  float mw = wave_max64(pwv);
  const float sx = mx > 0.0f ? 448.0f / mx * 0.9f : 1.0f;
  const float sw = mw > 0.0f ? 448.0f / mw * 0.9f : 1.0f;
  const float inv = 1.0f / (sx * sw);

  // ---- quantize slot + ds_write_b128 into A tile bu ----
  auto writeA = [&](int bu, int slot) {
    uint4 pk;
    pk.x = q2fp8<false>(xr[slot][0].x, xr[slot][0].y, 0u, sx);
    pk.x = q2fp8<true>(xr[slot][0].z, xr[slot][0].w, pk.x, sx);
    pk.y = q2fp8<false>(xr[slot][1].x, xr[slot][1].y, 0u, sx);
    pk.y = q2fp8<true>(xr[slot][1].z, xr[slot][1].w, pk.y, sx);
    pk.z = q2fp8<false>(xr[slot][2].x, xr[slot][2].y, 0u, sx);
    pk.z = q2fp8<true>(xr[slot][2].z, xr[slot][2].w, pk.z, sx);
    pk.w = q2fp8<false>(xr[slot][3].x, xr[slot][3].y, 0u, sx);
    pk.w = q2fp8<true>(xr[slot][3].z, xr[slot][3].w, pk.w, sx);
    *(uint4*)&As[bu * 8192 + xc * 2048 + xrow * 16] = pk;
  };

  // writeA(0): compiler waits x(0) (vmcnt(8)); x(1),B(0),B(1) stay in flight.
  writeA(0, 0);
  asm volatile("s_waitcnt vmcnt(2) lgkmcnt(0)" ::: "memory");  // B(0) landed; B(1) in flight
  __builtin_amdgcn_s_barrier();
  asm volatile("" ::: "memory");

#pragma unroll
  for (int kt = 0; kt < 8; ++kt) {
    const int cur3 = kt % 3;
    const int curA = kt & 1;
    if (kt < 6) {
      loadX(kt & 1, kt + 2);        // into the slot consumed last iteration
      stageB((kt + 2) % 3, kt + 2);
    }
#pragma unroll
    for (int kk = 0; kk < 2; ++kk) {
      long af[4], bf[4];
#pragma unroll
      for (int mi = 0; mi < 4; ++mi)
        af[mi] = *(const long*)&As[curA * 8192 + (kk * 2 + (quad >> 1)) * 2048 +
                                   (wm + mi * 16 + lr) * 16 + (quad & 1) * 8];
#pragma unroll
      for (int ni = 0; ni < 4; ++ni)
        bf[ni] = *(const long*)&Bs[cur3 * 16384 + (kk * 4 + quad) * 2048 + (wn + ni * 16 + lr) * 8];
      __builtin_amdgcn_s_setprio(1);
#pragma unroll
      for (int mi = 0; mi < 4; ++mi)
#pragma unroll
        for (int ni = 0; ni < 4; ++ni)
          acc[mi][ni] = __builtin_amdgcn_mfma_f32_16x16x32_fp8_fp8(af[mi], bf[ni], acc[mi][ni], 0, 0, 0);
      __builtin_amdgcn_s_setprio(0);
    }
    if (kt < 7) {
      // writeA reads xr slot loaded LAST iteration -> its wait is 1 iter old.
      writeA(curA ^ 1, (kt + 1) & 1);
      if (kt < 6) {
        // B(kt+1) issued last iter; leave x(kt+2)[4]+B(kt+2)[2] in flight.
        asm volatile("s_waitcnt vmcnt(6) lgkmcnt(0)" ::: "memory");
      } else {
        asm volatile("s_waitcnt vmcnt(0) lgkmcnt(0)" ::: "memory");
      }
      __builtin_amdgcn_s_barrier();
      asm volatile("" ::: "memory");
    }
  }

  // ---- epilogue: out = (acc + bias) * inv ; C layout col=lane&15, row=quad*4+reg ----
  float bn[4];
#pragma unroll
  for (int ni = 0; ni < 4; ++ni) bn[ni] = bias[n0 + wn + ni * 16 + lr];
#pragma unroll
  for (int mi = 0; mi < 4; ++mi) {
    const int gr = m0 + wm + mi * 16 + quad * 4;
#pragma unroll
    for (int ni = 0; ni < 4; ++ni) {
      const int gc = n0 + wn + ni * 16 + lr;
#pragma unroll
      for (int j = 0; j < 4; ++j)
        out[(size_t)(gr + j) * 512 + gc] = (acc[mi][ni][j] + bn[ni]) * inv;
    }
  }
}

extern "C" void kernel_launch(void* const* d_in, const int* in_sizes, int n_in,
                              void* d_out, int out_size, void* d_ws, size_t ws_size,
                              hipStream_t stream) {
  const float* x = (const float*)d_in[0];
  const float* w = (const float*)d_in[1];
  const float* bias = (const float*)d_in[2];
  float* out = (float*)d_out;

  const int K = 512, N = 512;
  const int M = in_sizes[0] / K;  // 131072

  float* ws_f = (float*)d_ws;                  // scalars region (unused now)
  float* px = ws_f + 16;                       // 2048 x-partials
  float* pw = ws_f + 16 + XBLOCKS;             // 64 w-partials
  u8* wq = (u8*)((char*)d_ws + 16384);         // 256 KB fp8 quantized weight (tiled)

  hipLaunchKernelGGL(amax2_kernel, dim3(XBLOCKS + WBLOCKS), dim3(256), 0, stream,
                     (const float4*)x, (M * K) / 4, (const float4*)w, (N * K) / 4, px, pw);
  hipLaunchKernelGGL(quant_w_kernel, dim3((N * K / 8) / 256), dim3(256), 0, stream,
                     w, wq, pw);
  hipLaunchKernelGGL(gemm_kernel, dim3((M / 128) * 2), dim3(512), 0, stream,
                     x, wq, bias, out, px, pw);
}

// Round 8
// 542.420 us; speedup vs baseline: 1.0354x; 1.0354x over previous
//
#include <hip/hip_runtime.h>

typedef unsigned short u16;
typedef unsigned int u32;
typedef unsigned char u8;
typedef __attribute__((ext_vector_type(4))) float f32x4;

// Clamp two floats to +-448 and pack as OCP e4m3fn into half of a u32 via the
// HW converter (RNE). HI selector must be a compile-time constant.
template <bool HI>
__device__ __forceinline__ u32 q2fp8(float a, float b, u32 old, float s) {
  a = fminf(448.0f, fmaxf(-448.0f, a * s));
  b = fminf(448.0f, fmaxf(-448.0f, b * s));
  return (u32)__builtin_amdgcn_cvt_pk_fp8_f32(a, b, (int)old, HI);
}

__device__ __forceinline__ float block_max(float m) {
#pragma unroll
  for (int off = 32; off > 0; off >>= 1)
    m = fmaxf(m, __shfl_down(m, off, 64));
  __shared__ float sm[4];
  int wv = threadIdx.x >> 6;
  if ((threadIdx.x & 63) == 0) sm[wv] = m;
  __syncthreads();
  float r = fmaxf(fmaxf(sm[0], sm[1]), fmaxf(sm[2], sm[3]));
  __syncthreads();
  return r;
}

#define XBLOCKS 2048
#define WBLOCKS 64

// blocks [0,2048): amax partials over x; [2048,2112): over w. No atomics, no init.
__global__ void amax2_kernel(const float4* __restrict__ x, int nx4,
                             const float4* __restrict__ w, int nw4,
                             float* __restrict__ px, float* __restrict__ pw) {
  int bid = blockIdx.x;
  const float4* p;
  int n4, b, nb;
  float* dst;
  if (bid < XBLOCKS) { p = x; n4 = nx4; dst = px; b = bid; nb = XBLOCKS; }
  else { p = w; n4 = nw4; dst = pw; b = bid - XBLOCKS; nb = WBLOCKS; }
  float m = 0.0f;
  int stride = nb * 256;
  for (int i = b * 256 + threadIdx.x; i < n4; i += stride) {
    float4 v = p[i];
    m = fmaxf(m, fmaxf(fmaxf(fabsf(v.x), fabsf(v.y)), fmaxf(fabsf(v.z), fabsf(v.w))));
  }
  m = block_max(m);
  if (threadIdx.x == 0) dst[b] = m;
}

// Full-wave max of 64 partials (bit-exact fmax reduction, order-independent).
__device__ __forceinline__ float wave_max64(float m) {
#pragma unroll
  for (int off = 32; off > 0; off >>= 1) m = fmaxf(m, __shfl_xor(m, off, 64));
  return m;
}

// Quantize w to fp8 e4m3 in a TILED layout: wq[kc][n][8] with kc = k>>3, i.e.
// wq[kc*4096 + n*8 + (k&7)] = q(w[n][k]). Computes sw from the pw partials
// itself (wave-local butterfly; fmax is exact so identical across kernels).
__global__ void quant_w_kernel(const float* __restrict__ w, u8* __restrict__ wq,
                               const float* __restrict__ pw) {
  float mw = wave_max64(pw[threadIdx.x & 63]);
  const float sw = mw > 0.0f ? 448.0f / mw * 0.9f : 1.0f;
  const int id = blockIdx.x * blockDim.x + threadIdx.x;  // 32768 = 64 kc * 512 n
  const int kc = id >> 9;
  const int n = id & 511;
  const float4* src = (const float4*)(w + (size_t)n * 512 + kc * 8);
  const float4 a = src[0];
  const float4 b = src[1];
  uint2 r;
  r.x = q2fp8<false>(a.x, a.y, 0u, sw);
  r.x = q2fp8<true>(a.z, a.w, r.x, sw);
  r.y = q2fp8<false>(b.x, b.y, 0u, sw);
  r.y = q2fp8<true>(b.z, b.w, r.y, sw);
  *(uint2*)&wq[(size_t)kc * 4096 + n * 8] = r;
}

// C = (q(x) @ q(w)^T + bias) * inv, fp8 MFMA.
// BM=64, BN=128, BK=64, 256 thr (4 waves 2x2; wave = 32x64 = 2x4 16x16 tiles,
// acc = 32 AGPR). SMALL BLOCKS, MANY STREAMS: LDS = exactly 32 KB
// (As 2x4KB dbuf + Bs 3x8KB ring) -> 5 blocks/CU = 20 waves/CU, five
// INDEPENDENT barrier domains per CU (vs 2 before) so one block's barrier
// stall is covered by four others. ~90 VGPR < 102 cap -> no spills (round-6
// lesson: the 2-slot fp32 x prefetch spilled).
// Early-quant pipeline per iter: issue loadX(kt+2) -> MFMA tile kt -> quantize
// x(kt+2) to xq[kt&1] (4 regs; the only vmem wait, ~1 MFMA-cluster aged) ->
// ds_write xq[(kt+1)&1] (quantized LAST iter, zero-wait) -> counted
// vmcnt(2) + raw s_barrier keeps B(kt+2) in flight across the barrier.
// Scales reduced in-kernel; Bs ring slot 2 doubles as reduce scratch before
// B(2) is staged (keeps LDS at exactly 32768 -> 5 blocks/CU).
// Grid swizzle: the 4 blocks sharing an x row-tile sit 8 apart in linear id ->
// same XCD under round-robin dispatch -> x tile read once per XCD L2.
__global__ void __launch_bounds__(256, 5) gemm_kernel(const float* __restrict__ x,
                                                      const u8* __restrict__ wq,
                                                      const float* __restrict__ bias,
                                                      float* __restrict__ out,
                                                      const float* __restrict__ px,
                                                      const float* __restrict__ pw) {
  __shared__ __align__(16) u8 As[2 * 4096];   // [bu:2][c:4][64][16] fp8, 8 KB
  __shared__ __align__(16) u8 Bs[3 * 8192];   // [bu:3][c:8][128][8] fp8, 24 KB
  float* smf = (float*)&Bs[2 * 8192];         // reduce scratch (before B(2) staged)
  const int tid = threadIdx.x;
  const int lane = tid & 63;
  const int wv = tid >> 6;          // 0..3
  const int quad = lane >> 4;
  const int lr = lane & 15;

  const int lin = blockIdx.x;
  const int xcd = lin & 7;
  const int rest = lin >> 3;
  const int jn = rest & 3;
  const int grp = rest >> 2;
  const int m0 = (grp * 8 + xcd) * 64;
  const int n0 = jn * 128;

  const int wm = (wv >> 1) * 32;    // wave row: 0 or 32
  const int wn = (wv & 1) * 64;     // wave col: 0 or 64
  const int xrow = tid >> 2;        // 0..63
  const int xc = tid & 3;           // 16-wide k-chunk this thread fills

  f32x4 acc[2][4] = {};
  float4 xr[4];                     // transient fp32 x tile (16 regs)
  uint4 xq[2];                      // quantized A slots (8 regs)

  // ---- scale partial reads FIRST (oldest in vmem queue) ----
  float pxv[8];
#pragma unroll
  for (int i = 0; i < 8; ++i) pxv[i] = px[tid + i * 256];
  float pwv = pw[lane];

  // ---- stage w tile (8 KB) for k-step kt into ring slot bu; wave wv owns 2 chunks ----
  auto stageB = [&](int bu, int kt) {
#pragma unroll
    for (int i = 0; i < 2; ++i) {
      const int c = wv * 2 + i;
      const u8* gp = wq + (size_t)(kt * 8 + c) * 4096 + (size_t)n0 * 8 + lane * 16;
      u8* lp = &Bs[bu * 8192 + c * 1024 + lane * 16];
      __builtin_amdgcn_global_load_lds((const __attribute__((address_space(1))) u32*)gp,
                                       (__attribute__((address_space(3))) u32*)lp, 16, 0, 0);
    }
  };
  // ---- issue x fp32 loads (64 B/thread = 16 consecutive floats) ----
  auto loadX = [&](int kt) {
    const float* p = x + (size_t)(m0 + xrow) * 512 + kt * 64 + xc * 16;
#pragma unroll
    for (int s = 0; s < 4; ++s) xr[s] = *(const float4*)(p + s * 4);
  };

  // ---- prologue loads: x(0), B(0), B(1) ----
  loadX(0);
  stageB(0, 0);
  stageB(1, 1);

  // ---- reduce scales (waits only px/pw; x/B stay outstanding) ----
  float m = pxv[0];
#pragma unroll
  for (int i = 1; i < 8; ++i) m = fmaxf(m, pxv[i]);
  m = wave_max64(m);
  if (lane == 0) smf[wv] = m;
  asm volatile("s_waitcnt lgkmcnt(0)" ::: "memory");
  __builtin_amdgcn_s_barrier();
  float mx = fmaxf(fmaxf(smf[0], smf[1]), fmaxf(smf[2], smf[3]));
  float mw = wave_max64(pwv);
  const float sx = mx > 0.0f ? 448.0f / mx * 0.9f : 1.0f;
  const float sw = mw > 0.0f ? 448.0f / mw * 0.9f : 1.0f;
  const float inv = 1.0f / (sx * sw);
  __builtin_amdgcn_s_barrier();  // all waves done with smf before B(2) staging

  // ---- quantize current xr into xq slot ----
  auto quantX = [&](int slot) {
    uint4 pk;
    pk.x = q2fp8<false>(xr[0].x, xr[0].y, 0u, sx);
    pk.x = q2fp8<true>(xr[0].z, xr[0].w, pk.x, sx);
    pk.y = q2fp8<false>(xr[1].x, xr[1].y, 0u, sx);
    pk.y = q2fp8<true>(xr[1].z, xr[1].w, pk.y, sx);
    pk.z = q2fp8<false>(xr[2].x, xr[2].y, 0u, sx);
    pk.z = q2fp8<true>(xr[2].z, xr[2].w, pk.z, sx);
    pk.w = q2fp8<false>(xr[3].x, xr[3].y, 0u, sx);
    pk.w = q2fp8<true>(xr[3].z, xr[3].w, pk.w, sx);
    xq[slot] = pk;
  };
  auto writeA = [&](int bu, int slot) {
    *(uint4*)&As[bu * 4096 + xc * 1024 + xrow * 16] = xq[slot];
  };

  // prologue pipeline: A(0) -> LDS buf0; A(1) -> xq[1]
  quantX(0);       // waits x(0); B(0),B(1) stay in flight
  writeA(0, 0);
  loadX(1);
  quantX(1);       // waits x(1)
  asm volatile("s_waitcnt lgkmcnt(0)" ::: "memory");
  __builtin_amdgcn_s_barrier();  // B(0) landed (older than x(1)); As buf0 visible
  asm volatile("" ::: "memory");

#pragma unroll
  for (int kt = 0; kt < 8; ++kt) {
    const int cur3 = kt % 3;
    const int curA = kt & 1;
    if (kt < 6) {
      loadX(kt + 2);                 // 4 loads, in flight across MFMA
      stageB((kt + 2) % 3, kt + 2);  // 2 loads, youngest
    }
#pragma unroll
    for (int kk = 0; kk < 2; ++kk) {
      long af[2], bf[4];
#pragma unroll
      for (int mi = 0; mi < 2; ++mi)
        af[mi] = *(const long*)&As[curA * 4096 + (kk * 2 + (quad >> 1)) * 1024 +
                                   (wm + mi * 16 + lr) * 16 + (quad & 1) * 8];
#pragma unroll
      for (int ni = 0; ni < 4; ++ni)
        bf[ni] = *(const long*)&Bs[cur3 * 8192 + (kk * 4 + quad) * 1024 + (wn + ni * 16 + lr) * 8];
      __builtin_amdgcn_s_setprio(1);
#pragma unroll
      for (int mi = 0; mi < 2; ++mi)
#pragma unroll
        for (int ni = 0; ni < 4; ++ni)
          acc[mi][ni] = __builtin_amdgcn_mfma_f32_16x16x32_fp8_fp8(af[mi], bf[ni], acc[mi][ni], 0, 0, 0);
      __builtin_amdgcn_s_setprio(0);
    }
    if (kt < 6) quantX(kt & 1);      // waits x(kt+2) (MFMA-aged); leaves B(kt+2)
    if (kt < 7) {
      writeA(curA ^ 1, (kt + 1) & 1);  // A(kt+1), quantized LAST iter: no wait
      if (kt < 6) {
        asm volatile("s_waitcnt vmcnt(2) lgkmcnt(0)" ::: "memory");  // B(kt+1) done
      } else {
        asm volatile("s_waitcnt vmcnt(0) lgkmcnt(0)" ::: "memory");
      }
      __builtin_amdgcn_s_barrier();
      asm volatile("" ::: "memory");
    }
  }

  // ---- epilogue: out = (acc + bias) * inv ; C layout col=lane&15, row=quad*4+reg ----
  float bn[4];
#pragma unroll
  for (int ni = 0; ni < 4; ++ni) bn[ni] = bias[n0 + wn + ni * 16 + lr];
#pragma unroll
  for (int mi = 0; mi < 2; ++mi) {
    const int gr = m0 + wm + mi * 16 + quad * 4;
#pragma unroll
    for (int ni = 0; ni < 4; ++ni) {
      const int gc = n0 + wn + ni * 16 + lr;
#pragma unroll
      for (int j = 0; j < 4; ++j)
        out[(size_t)(gr + j) * 512 + gc] = (acc[mi][ni][j] + bn[ni]) * inv;
    }
  }
}

extern "C" void kernel_launch(void* const* d_in, const int* in_sizes, int n_in,
                              void* d_out, int out_size, void* d_ws, size_t ws_size,
                              hipStream_t stream) {
  const float* x = (const float*)d_in[0];
  const float* w = (const float*)d_in[1];
  const float* bias = (const float*)d_in[2];
  float* out = (float*)d_out;

  const int K = 512, N = 512;
  const int M = in_sizes[0] / K;  // 131072

  float* ws_f = (float*)d_ws;                  // scalars region (unused now)
  float* px = ws_f + 16;                       // 2048 x-partials
  float* pw = ws_f + 16 + XBLOCKS;             // 64 w-partials
  u8* wq = (u8*)((char*)d_ws + 16384);         // 256 KB fp8 quantized weight (tiled)

  hipLaunchKernelGGL(amax2_kernel, dim3(XBLOCKS + WBLOCKS), dim3(256), 0, stream,
                     (const float4*)x, (M * K) / 4, (const float4*)w, (N * K) / 4, px, pw);
  hipLaunchKernelGGL(quant_w_kernel, dim3((N * K / 8) / 256), dim3(256), 0, stream,
                     w, wq, pw);
  hipLaunchKernelGGL(gemm_kernel, dim3((M / 64) * (N / 128)), dim3(256), 0, stream,
                     x, wq, bias, out, px, pw);
}

// Round 9
// 527.333 us; speedup vs baseline: 1.0650x; 1.0286x over previous
//
#include <hip/hip_runtime.h>

typedef unsigned short u16;
typedef unsigned int u32;
typedef unsigned char u8;
typedef __attribute__((ext_vector_type(4))) float f32x4;

// Clamp two floats to +-448 and pack as OCP e4m3fn into half of a u32 via the
// HW converter (RNE). HI selector must be a compile-time constant.
template <bool HI>
__device__ __forceinline__ u32 q2fp8(float a, float b, u32 old, float s) {
  a = fminf(448.0f, fmaxf(-448.0f, a * s));
  b = fminf(448.0f, fmaxf(-448.0f, b * s));
  return (u32)__builtin_amdgcn_cvt_pk_fp8_f32(a, b, (int)old, HI);
}

__device__ __forceinline__ float block_max(float m) {
#pragma unroll
  for (int off = 32; off > 0; off >>= 1)
    m = fmaxf(m, __shfl_down(m, off, 64));
  __shared__ float sm[4];
  int wv = threadIdx.x >> 6;
  if ((threadIdx.x & 63) == 0) sm[wv] = m;
  __syncthreads();
  float r = fmaxf(fmaxf(sm[0], sm[1]), fmaxf(sm[2], sm[3]));
  __syncthreads();
  return r;
}

#define XBLOCKS 2048
#define WBLOCKS 64

// blocks [0,2048): amax partials over x; [2048,2112): over w. No atomics, no init.
__global__ void amax2_kernel(const float4* __restrict__ x, int nx4,
                             const float4* __restrict__ w, int nw4,
                             float* __restrict__ px, float* __restrict__ pw) {
  int bid = blockIdx.x;
  const float4* p;
  int n4, b, nb;
  float* dst;
  if (bid < XBLOCKS) { p = x; n4 = nx4; dst = px; b = bid; nb = XBLOCKS; }
  else { p = w; n4 = nw4; dst = pw; b = bid - XBLOCKS; nb = WBLOCKS; }
  float m = 0.0f;
  int stride = nb * 256;
  for (int i = b * 256 + threadIdx.x; i < n4; i += stride) {
    float4 v = p[i];
    m = fmaxf(m, fmaxf(fmaxf(fabsf(v.x), fabsf(v.y)), fmaxf(fabsf(v.z), fabsf(v.w))));
  }
  m = block_max(m);
  if (threadIdx.x == 0) dst[b] = m;
}

// Full-wave max of 64 partials (bit-exact fmax reduction, order-independent).
__device__ __forceinline__ float wave_max64(float m) {
#pragma unroll
  for (int off = 32; off > 0; off >>= 1) m = fmaxf(m, __shfl_xor(m, off, 64));
  return m;
}

// Quantize w to fp8 e4m3 in a TILED layout: wq[kc][n][8] with kc = k>>3, i.e.
// wq[kc*4096 + n*8 + (k&7)] = q(w[n][k]). Computes sw from the pw partials
// itself (wave-local butterfly; fmax is exact so identical across kernels).
__global__ void quant_w_kernel(const float* __restrict__ w, u8* __restrict__ wq,
                               const float* __restrict__ pw) {
  float mw = wave_max64(pw[threadIdx.x & 63]);
  const float sw = mw > 0.0f ? 448.0f / mw * 0.9f : 1.0f;
  const int id = blockIdx.x * blockDim.x + threadIdx.x;  // 32768 = 64 kc * 512 n
  const int kc = id >> 9;
  const int n = id & 511;
  const float4* src = (const float4*)(w + (size_t)n * 512 + kc * 8);
  const float4 a = src[0];
  const float4 b = src[1];
  uint2 r;
  r.x = q2fp8<false>(a.x, a.y, 0u, sw);
  r.x = q2fp8<true>(a.z, a.w, r.x, sw);
  r.y = q2fp8<false>(b.x, b.y, 0u, sw);
  r.y = q2fp8<true>(b.z, b.w, r.y, sw);
  *(uint2*)&wq[(size_t)kc * 4096 + n * 8] = r;
}

// C = (q(x) @ q(w)^T + bias) * inv, fp8 MFMA.  BM=128, BN=256, BK=64, 512 thr
// (8 waves 2x4; wave computes 64x64 = 4x4 16x16 tiles, acc = 64 AGPR).
// Round-5 geometry (best measured) + TOP-OF-ITER quant/write:
//   As[curA^1] is safe to write at the TOP of iter kt (its iter-(kt-1) readers
//   were lgkm-drained by the previous barrier), so the quant+ds_write of
//   x(kt+1) happens BEFORE iter kt's MFMAs. The x wait (vmcnt(2)) is then a
//   full iteration old (~1300 cyc cover vs ~640 when post-MFMA), and the cvt
//   VALU work overlaps other waves' MFMA phases. Zero extra registers (the
//   round-6 spill trap is avoided: single fp32 xr buffer).
// Wait ledger per iter (all >=1-iter aged): vmcnt(2) at quant (leaves B(kt+1));
// vmcnt(6)+lgkmcnt(0) at the barrier (drains only B(kt+1); x(kt+2)+B(kt+2)
// stay in flight ACROSS the barrier). B ring depth 3; A double-buffered.
// Scales reduced in-kernel from px/pw partials (their reads are the oldest
// vmem ops, so the reduce's wait leaves the prologue x/B loads outstanding).
// LDS 64 KB + 32 B -> 2 blocks/CU; 4 waves/EU.
// Grid swizzle: the 2 blocks sharing an x row-tile have linear ids differing by
// 8 -> same XCD under round-robin dispatch -> 2nd x read hits that XCD's L2.
__global__ void __launch_bounds__(512, 4) gemm_kernel(const float* __restrict__ x,
                                                      const u8* __restrict__ wq,
                                                      const float* __restrict__ bias,
                                                      float* __restrict__ out,
                                                      const float* __restrict__ px,
                                                      const float* __restrict__ pw) {
  __shared__ __align__(16) u8 As[2 * 8192];    // [bu:2][c:4][128][16] fp8, 16 KB
  __shared__ __align__(16) u8 Bs[3 * 16384];   // [bu:3][c:8][256][8]  fp8, 48 KB
  __shared__ float sm8[8];
  const int tid = threadIdx.x;
  const int lane = tid & 63;
  const int wv = tid >> 6;          // 0..7
  const int quad = lane >> 4;
  const int lr = lane & 15;

  const int lin = blockIdx.x;
  const int xcd = lin & 7;
  const int jn = (lin >> 3) & 1;
  const int grp = lin >> 4;
  const int m0 = (grp * 8 + xcd) * 128;
  const int n0 = jn * 256;

  const int wm = (wv >> 2) * 64;    // wave row: 0 or 64
  const int wn = (wv & 3) * 64;     // wave col: 0,64,128,192
  const int xrow = tid >> 2;        // 0..127
  const int xc = tid & 3;           // 16-wide k-chunk this thread fills

  f32x4 acc[4][4] = {};
  float4 xr[4];                     // single transient fp32 x tile (16 regs)

  // ---- scale partial reads FIRST (oldest in the vmem queue) ----
  float pxv[4];
#pragma unroll
  for (int i = 0; i < 4; ++i) pxv[i] = px[tid + i * 512];
  float pwv = pw[lane];

  // ---- stage w tile (16 KB) for k-step kt into ring slot bu; wave wv owns chunk wv ----
  auto stageB = [&](int bu, int kt) {
#pragma unroll
    for (int i = 0; i < 2; ++i) {
      const u8* gp = wq + (size_t)(kt * 8 + wv) * 4096 + (size_t)n0 * 8 + i * 1024 + lane * 16;
      u8* lp = &Bs[bu * 16384 + wv * 2048 + i * 1024 + lane * 16];
      __builtin_amdgcn_global_load_lds((const __attribute__((address_space(1))) u32*)gp,
                                       (__attribute__((address_space(3))) u32*)lp, 16, 0, 0);
    }
  };
  // ---- issue x fp32 loads (64 B/thread = 16 consecutive floats) ----
  auto loadX = [&](int kt) {
    const float* p = x + (size_t)(m0 + xrow) * 512 + kt * 64 + xc * 16;
#pragma unroll
    for (int s = 0; s < 4; ++s) xr[s] = *(const float4*)(p + s * 4);
  };

  // ---- prologue loads: x(0), B(0) ----
  loadX(0);
  stageB(0, 0);

  // ---- reduce scales (waits only px/pw, the oldest loads; x/B stay in flight) ----
  float m = fmaxf(fmaxf(pxv[0], pxv[1]), fmaxf(pxv[2], pxv[3]));
  m = wave_max64(m);
  if (lane == 0) sm8[wv] = m;
  asm volatile("s_waitcnt lgkmcnt(0)" ::: "memory");
  __builtin_amdgcn_s_barrier();
  float mx = sm8[0];
#pragma unroll
  for (int i = 1; i < 8; ++i) mx = fmaxf(mx, sm8[i]);
  float mw = wave_max64(pwv);
  const float sx = mx > 0.0f ? 448.0f / mx * 0.9f : 1.0f;
  const float sw = mw > 0.0f ? 448.0f / mw * 0.9f : 1.0f;
  const float inv = 1.0f / (sx * sw);

  // ---- quantize xr (HW cvt) + ds_write_b128 into A tile bu ----
  auto quantWriteA = [&](int bu) {
    uint4 pk;
    pk.x = q2fp8<false>(xr[0].x, xr[0].y, 0u, sx);
    pk.x = q2fp8<true>(xr[0].z, xr[0].w, pk.x, sx);
    pk.y = q2fp8<false>(xr[1].x, xr[1].y, 0u, sx);
    pk.y = q2fp8<true>(xr[1].z, xr[1].w, pk.y, sx);
    pk.z = q2fp8<false>(xr[2].x, xr[2].y, 0u, sx);
    pk.z = q2fp8<true>(xr[2].z, xr[2].w, pk.z, sx);
    pk.w = q2fp8<false>(xr[3].x, xr[3].y, 0u, sx);
    pk.w = q2fp8<true>(xr[3].z, xr[3].w, pk.w, sx);
    *(uint4*)&As[bu * 8192 + xc * 2048 + xrow * 16] = pk;
  };

  // A(0) -> LDS buf0 (waits x(0), vmcnt(2): B(0) stays in flight); then x(1), B(1).
  quantWriteA(0);
  loadX(1);
  stageB(1, 1);
  // Drain B(0) only: outstanding [B(0)2, x(1)4, B(1)2] -> vmcnt(6).
  asm volatile("s_waitcnt vmcnt(6) lgkmcnt(0)" ::: "memory");
  __builtin_amdgcn_s_barrier();
  asm volatile("" ::: "memory");

  // Steady-state entry queue: [x(kt+1) x4, B(kt+1) x2].
#pragma unroll
  for (int kt = 0; kt < 8; ++kt) {
    const int cur3 = kt % 3;
    const int curA = kt & 1;
    // Top-of-iter: quant x(kt+1) -> As[curA^1] (safe: last iter's readers are
    // lgkm-drained). vmcnt(2) wait is 1 iter old; leaves B(kt+1) in flight.
    if (kt < 7) quantWriteA(curA ^ 1);
    if (kt < 6) {
      loadX(kt + 2);                 // 4 loads, in flight across MFMA + barrier
      stageB((kt + 2) % 3, kt + 2);  // 2 loads, youngest
    }
#pragma unroll
    for (int kk = 0; kk < 2; ++kk) {
      long af[4], bf[4];
#pragma unroll
      for (int mi = 0; mi < 4; ++mi)
        af[mi] = *(const long*)&As[curA * 8192 + (kk * 2 + (quad >> 1)) * 2048 +
                                   (wm + mi * 16 + lr) * 16 + (quad & 1) * 8];
#pragma unroll
      for (int ni = 0; ni < 4; ++ni)
        bf[ni] = *(const long*)&Bs[cur3 * 16384 + (kk * 4 + quad) * 2048 + (wn + ni * 16 + lr) * 8];
      __builtin_amdgcn_s_setprio(1);
#pragma unroll
      for (int mi = 0; mi < 4; ++mi)
#pragma unroll
        for (int ni = 0; ni < 4; ++ni)
          acc[mi][ni] = __builtin_amdgcn_mfma_f32_16x16x32_fp8_fp8(af[mi], bf[ni], acc[mi][ni], 0, 0, 0);
      __builtin_amdgcn_s_setprio(0);
    }
    if (kt < 7) {
      if (kt < 6) {
        // Outstanding [B(kt+1)2, x(kt+2)4, B(kt+2)2]: drain only B(kt+1)
        // (1 iter old); x(kt+2)+B(kt+2) cross the barrier in flight.
        asm volatile("s_waitcnt vmcnt(6) lgkmcnt(0)" ::: "memory");
      } else {
        asm volatile("s_waitcnt vmcnt(0) lgkmcnt(0)" ::: "memory");  // B(7), 1 iter old
      }
      __builtin_amdgcn_s_barrier();
      asm volatile("" ::: "memory");
    }
  }

  // ---- epilogue: out = (acc + bias) * inv ; C layout col=lane&15, row=quad*4+reg ----
  float bn[4];
#pragma unroll
  for (int ni = 0; ni < 4; ++ni) bn[ni] = bias[n0 + wn + ni * 16 + lr];
#pragma unroll
  for (int mi = 0; mi < 4; ++mi) {
    const int gr = m0 + wm + mi * 16 + quad * 4;
#pragma unroll
    for (int ni = 0; ni < 4; ++ni) {
      const int gc = n0 + wn + ni * 16 + lr;
#pragma unroll
      for (int j = 0; j < 4; ++j)
        out[(size_t)(gr + j) * 512 + gc] = (acc[mi][ni][j] + bn[ni]) * inv;
    }
  }
}

extern "C" void kernel_launch(void* const* d_in, const int* in_sizes, int n_in,
                              void* d_out, int out_size, void* d_ws, size_t ws_size,
                              hipStream_t stream) {
  const float* x = (const float*)d_in[0];
  const float* w = (const float*)d_in[1];
  const float* bias = (const float*)d_in[2];
  float* out = (float*)d_out;

  const int K = 512, N = 512;
  const int M = in_sizes[0] / K;  // 131072

  float* ws_f = (float*)d_ws;                  // scalars region (unused now)
  float* px = ws_f + 16;                       // 2048 x-partials
  float* pw = ws_f + 16 + XBLOCKS;             // 64 w-partials
  u8* wq = (u8*)((char*)d_ws + 16384);         // 256 KB fp8 quantized weight (tiled)

  hipLaunchKernelGGL(amax2_kernel, dim3(XBLOCKS + WBLOCKS), dim3(256), 0, stream,
                     (const float4*)x, (M * K) / 4, (const float4*)w, (N * K) / 4, px, pw);
  hipLaunchKernelGGL(quant_w_kernel, dim3((N * K / 8) / 256), dim3(256), 0, stream,
                     w, wq, pw);
  hipLaunchKernelGGL(gemm_kernel, dim3((M / 128) * 2), dim3(512), 0, stream,
                     x, wq, bias, out, px, pw);
}